// Round 5
// baseline (653.173 us; speedup 1.0000x reference)
//
#include <hip/hip_runtime.h>
#include <math.h>

#define A_NODES 50000
#define FEAT 128
#define EDGES 500000
#define NRBF 20
#define CUTOFF_F 5.0f
#define PI_OVER_CUTOFF 0.6283185307179586f

typedef unsigned int uint32;
typedef unsigned short ushort16;
typedef short bf16x8 __attribute__((ext_vector_type(8)));
typedef float f32x4 __attribute__((ext_vector_type(4)));
typedef float f32x2 __attribute__((ext_vector_type(2)));

__device__ __forceinline__ ushort16 f2bf(float f) {
    union { float f; uint32 u; } v; v.f = f;
    uint32 r = (v.u + 0x7fffu + ((v.u >> 16) & 1u)) >> 16;   // RNE
    return (ushort16)r;
}
__device__ __forceinline__ uint32 packbf(float a, float b) {
    return (uint32)f2bf(a) | ((uint32)f2bf(b) << 16);
}
__device__ __forceinline__ float bf_lo(uint32 u) { return __uint_as_float(u << 16); }
__device__ __forceinline__ float bf_hi(uint32 u) { return __uint_as_float(u & 0xffff0000u); }

#if __has_builtin(__builtin_amdgcn_fdot2_f32_bf16)
typedef __bf16 bf16x2 __attribute__((ext_vector_type(2)));
__device__ __forceinline__ float dot2(uint32 a, uint32 b, float c) {
    return __builtin_amdgcn_fdot2_f32_bf16(
        __builtin_bit_cast(bf16x2, a), __builtin_bit_cast(bf16x2, b), c, false);
}
#else
__device__ __forceinline__ float dot2(uint32 a, uint32 b, float c) {
    return fmaf(bf_hi(a), bf_hi(b), fmaf(bf_lo(a), bf_lo(b), c));
}
#endif

#define NB_CVT 9375            // ceil(50000*384/8 / 256)
#define NB_HIST 1954           // ceil(500000 / 256)
#define NB_PACK 271            // ceil(69376 / 256)

// ---------------------------------------------------------------------------
// Fused prep: vec_cvt + hist + weight packing (all independent) in one launch.
// ---------------------------------------------------------------------------
__global__ __launch_bounds__(256) void prep_kernel(
    const float* __restrict__ vin, uint4* __restrict__ vbf, int use_vbf,
    const int* __restrict__ idx_j, int* __restrict__ hist,
    const float* __restrict__ W1, const float* __restrict__ W2,
    const float* __restrict__ Wr,
    ushort16* __restrict__ w1pk, ushort16* __restrict__ w2pk,
    uint32* __restrict__ wrpk)
{
    const int b = blockIdx.x;
    if (b < NB_CVT) {
        if (!use_vbf) return;
        const size_t t = (size_t)b * 256 + threadIdx.x;   // 8-float chunk
        const size_t n8 = (size_t)A_NODES * 384 / 8;
        if (t < n8) {
            const float4 f0 = ((const float4*)vin)[2 * t];
            const float4 f1 = ((const float4*)vin)[2 * t + 1];
            uint4 o;
            o.x = packbf(f0.x, f0.y); o.y = packbf(f0.z, f0.w);
            o.z = packbf(f1.x, f1.y); o.w = packbf(f1.z, f1.w);
            vbf[t] = o;
        }
    } else if (b < NB_CVT + NB_HIST) {
        const int e = (b - NB_CVT) * 256 + threadIdx.x;
        if (e < EDGES) atomicAdd(&hist[idx_j[e]], 1);
    } else {
        const int t = (b - NB_CVT - NB_HIST) * 256 + threadIdx.x;
        if (t < 16384) {
            const int jj = t & 7, l = (t >> 3) & 63, kk = (t >> 9) & 3, nt = t >> 11;
            const int col = (l & 15) + 16 * nt;
            const int k   = kk * 32 + (l >> 4) * 8 + jj;
            w1pk[t] = f2bf(W1[k * 128 + col]);
        } else if (t < 16384 + 49152) {
            const int u = t - 16384;
            const int jj = u & 7, l = (u >> 3) & 63, kk = (u >> 9) & 3, nt = u >> 11;
            const int col = (l & 15) + 16 * nt;
            const int k   = kk * 32 + (l >> 4) * 8 + jj;
            w2pk[u] = f2bf(W2[k * 384 + col]);
        } else if (t < 16384 + 49152 + 3840) {
            const int u = t - 16384 - 49152;
            const int m = u / 384, col = u % 384;
            wrpk[u] = packbf(Wr[(2 * m) * 384 + col], Wr[(2 * m + 1) * 384 + col]);
        }
    }
}

// ---------------------------------------------------------------------------
// Node MLP via MFMA. 16 nodes/block, 4 waves.
// ---------------------------------------------------------------------------
__global__ __launch_bounds__(256) void node_mlp_kernel(
    const float* __restrict__ scalars,
    const ushort16* __restrict__ w1pk, const float* __restrict__ bias1,
    const ushort16* __restrict__ w2pk, const float* __restrict__ bias2,
    ushort16* __restrict__ s_bf)
{
    __shared__ ushort16 sc[16][136];
    __shared__ ushort16 hd[16][136];
    const int tx   = threadIdx.x;
    const int lane = tx & 63;
    const int wv   = tx >> 6;                 // 0..3
    const int base = blockIdx.x * 16;

    {
        const int row = tx >> 4;              // 0..15
        const int cs  = (tx & 15) * 8;        // 0,8,...,120
        const float* src = scalars + (size_t)(base + row) * FEAT + cs;
        const float4 f0 = *(const float4*)src;
        const float4 f1 = *(const float4*)(src + 4);
        bf16x8 tmp;
        tmp[0] = (short)f2bf(f0.x); tmp[1] = (short)f2bf(f0.y);
        tmp[2] = (short)f2bf(f0.z); tmp[3] = (short)f2bf(f0.w);
        tmp[4] = (short)f2bf(f1.x); tmp[5] = (short)f2bf(f1.y);
        tmp[6] = (short)f2bf(f1.z); tmp[7] = (short)f2bf(f1.w);
        *(bf16x8*)&sc[row][cs] = tmp;
    }
    __syncthreads();

    const int arow = lane & 15;
    const int kgrp = lane >> 4;               // 0..3

    // ---- layer 1 ----
    f32x4 acc0 = {0.f, 0.f, 0.f, 0.f};
    f32x4 acc1 = {0.f, 0.f, 0.f, 0.f};
    #pragma unroll
    for (int kk = 0; kk < 4; ++kk) {
        const bf16x8 a  = *(const bf16x8*)&sc[arow][kk * 32 + kgrp * 8];
        const bf16x8 b0 = *(const bf16x8*)(w1pk + (((size_t)(wv * 2 + 0) * 4 + kk) * 64 + lane) * 8);
        const bf16x8 b1 = *(const bf16x8*)(w1pk + (((size_t)(wv * 2 + 1) * 4 + kk) * 64 + lane) * 8);
        acc0 = __builtin_amdgcn_mfma_f32_16x16x32_bf16(a, b0, acc0, 0, 0, 0);
        acc1 = __builtin_amdgcn_mfma_f32_16x16x32_bf16(a, b1, acc1, 0, 0, 0);
    }
    {
        const int c0 = wv * 32 + (lane & 15);
        const int c1 = c0 + 16;
        const float bb0 = bias1[c0], bb1 = bias1[c1];
        #pragma unroll
        for (int r = 0; r < 4; ++r) {
            const int row = kgrp * 4 + r;
            float x0 = acc0[r] + bb0;
            float x1 = acc1[r] + bb1;
            x0 = x0 / (1.0f + __expf(-x0));
            x1 = x1 / (1.0f + __expf(-x1));
            hd[row][c0] = f2bf(x0);
            hd[row][c1] = f2bf(x1);
        }
    }
    __syncthreads();

    // ---- layer 2 ----
    f32x4 acc[6];
    #pragma unroll
    for (int n = 0; n < 6; ++n) acc[n] = (f32x4){0.f, 0.f, 0.f, 0.f};
    #pragma unroll
    for (int kk = 0; kk < 4; ++kk) {
        const bf16x8 a = *(const bf16x8*)&hd[arow][kk * 32 + kgrp * 8];
        #pragma unroll
        for (int n = 0; n < 6; ++n) {
            const bf16x8 b = *(const bf16x8*)(w2pk + (((size_t)(wv * 6 + n) * 4 + kk) * 64 + lane) * 8);
            acc[n] = __builtin_amdgcn_mfma_f32_16x16x32_bf16(a, b, acc[n], 0, 0, 0);
        }
    }
    #pragma unroll
    for (int n = 0; n < 6; ++n) {
        const int col = (wv * 6 + n) * 16 + (lane & 15);
        const float bb = bias2[col];
        #pragma unroll
        for (int r = 0; r < 4; ++r) {
            const int row = kgrp * 4 + r;
            s_bf[(size_t)(base + row) * 384 + col] = f2bf(acc[n][r] + bb);
        }
    }
}

// ---------------------------------------------------------------------------
// CSR scan
// ---------------------------------------------------------------------------
__global__ __launch_bounds__(1024) void scan_kernel(
    const int* __restrict__ hist, int* __restrict__ offsets,
    int* __restrict__ cursor)
{
    __shared__ int part[1024];
    const int t = threadIdx.x;
    const int CH = (A_NODES + 1023) / 1024;

    int sum = 0;
    for (int k = 0; k < CH; ++k) {
        const int idx = t * CH + k;
        if (idx < A_NODES) sum += hist[idx];
    }
    part[t] = sum;
    __syncthreads();
    for (int off = 1; off < 1024; off <<= 1) {
        const int v = (t >= off) ? part[t - off] : 0;
        __syncthreads();
        part[t] += v;
        __syncthreads();
    }
    int run = part[t] - sum;
    for (int k = 0; k < CH; ++k) {
        const int idx = t * CH + k;
        if (idx < A_NODES) {
            offsets[idx] = run;
            cursor[idx]  = run;
            run += hist[idx];
        }
    }
    if (t == 0) offsets[A_NODES] = EDGES;
}

// ---------------------------------------------------------------------------
// Edge prep FUSED with scatter: writes edata[pos] directly (nontemporal).
// 16 dwords: [0..9] rbf*invn*fc bf16x2 pairs; [10..12] unit dir; [13] fc;
// [14] idx_i bits; [15] pad.
// ---------------------------------------------------------------------------
__global__ __launch_bounds__(256) void edge_prep_kernel(
    const float* __restrict__ directions,
    const int* __restrict__ idx_i, const int* __restrict__ idx_j,
    int* __restrict__ cursor,
    float* __restrict__ edata)
{
    const int e = blockIdx.x * 256 + threadIdx.x;
    if (e >= EDGES) return;
    const int j   = idx_j[e];
    const int pos = atomicAdd(&cursor[j], 1);
    const int i   = idx_i[e];
    const float d0 = directions[(size_t)e * 3 + 0];
    const float d1 = directions[(size_t)e * 3 + 1];
    const float d2 = directions[(size_t)e * 3 + 2];
    const float nr   = sqrtf(d0 * d0 + d1 * d1 + d2 * d2);
    const float invn = 1.0f / nr;
    const float x = PI_OVER_CUTOFF * nr;
    float sx, cx;
    sincosf(x, &sx, &cx);
    const float fc = (nr < CUTOFF_F) ? 0.5f * (cx + 1.0f) : 0.0f;
    const float scale = invn * fc;
    const float twoc = 2.0f * cx;

    float out16[16];
    float s_odd = sx;      // sin((2m+1)x)
    float s_prev = 0.0f;   // sin(2m x)
    #pragma unroll
    for (int m = 0; m < 10; ++m) {
        const float s_even = twoc * s_odd - s_prev;       // sin((2m+2)x)
        out16[m] = __uint_as_float(packbf(s_odd * scale, s_even * scale));
        const float s_next = twoc * s_even - s_odd;       // sin((2m+3)x)
        s_prev = s_even;
        s_odd  = s_next;
    }
    out16[10] = d0 * invn;
    out16[11] = d1 * invn;
    out16[12] = d2 * invn;
    out16[13] = fc;
    out16[14] = __int_as_float(i);
    out16[15] = 0.0f;

    f32x4* dst = (f32x4*)(edata + (size_t)pos * 16);
    f32x4 q0 = {out16[0],  out16[1],  out16[2],  out16[3]};
    f32x4 q1 = {out16[4],  out16[5],  out16[6],  out16[7]};
    f32x4 q2 = {out16[8],  out16[9],  out16[10], out16[11]};
    f32x4 q3 = {out16[12], out16[13], out16[14], out16[15]};
    __builtin_nontemporal_store(q0, dst + 0);
    __builtin_nontemporal_store(q1, dst + 1);
    __builtin_nontemporal_store(q2, dst + 2);
    __builtin_nontemporal_store(q3, dst + 3);
}

// ---------------------------------------------------------------------------
// Gather: 2 nodes/block, 3 SEGMENT-waves per node (384 threads).
//   seg0: delta_s cols          (needs s0)
//   seg1: v[i]*g1 part of d_v   (needs s1, v[i])
//   seg2: u*g2 part of d_v      (needs s2, unit dir)
// Each wave holds only 10 uint2 Wr pairs (20 VGPRs) -> register-resident.
// delta_v halves combined via small LDS reduction.
// ---------------------------------------------------------------------------
template <int VBF>
__global__ __launch_bounds__(384, 6) void gather_kernel(
    const ushort16* __restrict__ s_bf,
    const ushort16* __restrict__ v_bf,
    const float* __restrict__ vectors_f32,
    const uint32* __restrict__ wrpk, const float* __restrict__ br,
    const float* __restrict__ edata,
    const int* __restrict__ offsets,
    float* __restrict__ out_v, float* __restrict__ out_s)
{
    const int lane = threadIdx.x & 63;
    const int wv   = __builtin_amdgcn_readfirstlane(threadIdx.x >> 6);  // 0..5
    const int nsub = wv / 3;          // 0..1  (node within block)
    const int seg  = wv % 3;          // 0..2  (segment role)
    const int j    = blockIdx.x * 2 + nsub;
    const int c0   = lane * 2;
    const int soff = seg * 128 + c0;  // ushort offset within a 384-col row

    // 10 weight pairs for this segment (cols c0, c0+1), pinned in VGPRs
#define LDW(m) (*(const uint2*)(wrpk + (m) * 384 + soff))
    uint2 w0 = LDW(0), w1 = LDW(1), w2 = LDW(2), w3 = LDW(3), w4 = LDW(4);
    uint2 w5 = LDW(5), w6 = LDW(6), w7 = LDW(7), w8 = LDW(8), w9 = LDW(9);
#undef LDW
    asm volatile("" : "+v"(w0.x),"+v"(w0.y),"+v"(w1.x),"+v"(w1.y),
                      "+v"(w2.x),"+v"(w2.y),"+v"(w3.x),"+v"(w3.y),
                      "+v"(w4.x),"+v"(w4.y),"+v"(w5.x),"+v"(w5.y),
                      "+v"(w6.x),"+v"(w6.y),"+v"(w7.x),"+v"(w7.y),
                      "+v"(w8.x),"+v"(w8.y),"+v"(w9.x),"+v"(w9.y));
    const float2 brv = *(const float2*)(br + soff);

    const int beg = offsets[j];
    const int end = offsets[j + 1];

    f32x2 acc = {0.f, 0.f};                   // seg0: delta_s
    f32x2 av0 = {0.f, 0.f}, av1 = {0.f, 0.f}, av2 = {0.f, 0.f};  // seg1/2 parts

    if (beg < end) {
        // prefetch gathers for first edge
        int i_c = __float_as_int(edata[(size_t)beg * 16 + 14]);
        uint32 s_c = *(const uint32*)(s_bf + (size_t)i_c * 384 + soff);
        uint32 vb0_c = 0, vb1_c = 0, vb2_c = 0;
        f32x2  vf0_c = {0,0}, vf1_c = {0,0}, vf2_c = {0,0};
        if (seg == 1) {
            if (VBF) {
                const ushort16* vrow = v_bf + (size_t)i_c * 384;
                vb0_c = *(const uint32*)(vrow + c0);
                vb1_c = *(const uint32*)(vrow + 128 + c0);
                vb2_c = *(const uint32*)(vrow + 256 + c0);
            } else {
                const float* vrow = vectors_f32 + (size_t)i_c * 384;
                vf0_c = *(const f32x2*)(vrow + c0);
                vf1_c = *(const f32x2*)(vrow + 128 + c0);
                vf2_c = *(const f32x2*)(vrow + 256 + c0);
            }
        }

        for (int p = beg; p < end; ++p) {
            // prefetch next edge's gathers (clamped)
            const int pn = (p + 1 < end) ? p + 1 : p;
            const int i_n = __float_as_int(edata[(size_t)pn * 16 + 14]);
            const uint32 s_n = *(const uint32*)(s_bf + (size_t)i_n * 384 + soff);
            uint32 vb0_n = 0, vb1_n = 0, vb2_n = 0;
            f32x2  vf0_n = {0,0}, vf1_n = {0,0}, vf2_n = {0,0};
            if (seg == 1) {
                if (VBF) {
                    const ushort16* vrow = v_bf + (size_t)i_n * 384;
                    vb0_n = *(const uint32*)(vrow + c0);
                    vb1_n = *(const uint32*)(vrow + 128 + c0);
                    vb2_n = *(const uint32*)(vrow + 256 + c0);
                } else {
                    const float* vrow = vectors_f32 + (size_t)i_n * 384;
                    vf0_n = *(const f32x2*)(vrow + c0);
                    vf1_n = *(const f32x2*)(vrow + 128 + c0);
                    vf2_n = *(const f32x2*)(vrow + 256 + c0);
                }
            }

            // wave-uniform edata fields (64B row = 1 cache line)
            const float* ed = edata + (size_t)p * 16;
            const uint32 b0 = __float_as_uint(ed[0]), b1 = __float_as_uint(ed[1]);
            const uint32 b2 = __float_as_uint(ed[2]), b3 = __float_as_uint(ed[3]);
            const uint32 b4 = __float_as_uint(ed[4]), b5 = __float_as_uint(ed[5]);
            const uint32 b6 = __float_as_uint(ed[6]), b7 = __float_as_uint(ed[7]);
            const uint32 b8 = __float_as_uint(ed[8]), b9 = __float_as_uint(ed[9]);
            const float fcv = ed[13];

            float rA = fcv * brv.x, rB = fcv * brv.y;
            rA = dot2(b0, w0.x, rA); rB = dot2(b0, w0.y, rB);
            rA = dot2(b1, w1.x, rA); rB = dot2(b1, w1.y, rB);
            rA = dot2(b2, w2.x, rA); rB = dot2(b2, w2.y, rB);
            rA = dot2(b3, w3.x, rA); rB = dot2(b3, w3.y, rB);
            rA = dot2(b4, w4.x, rA); rB = dot2(b4, w4.y, rB);
            rA = dot2(b5, w5.x, rA); rB = dot2(b5, w5.y, rB);
            rA = dot2(b6, w6.x, rA); rB = dot2(b6, w6.y, rB);
            rA = dot2(b7, w7.x, rA); rB = dot2(b7, w7.y, rB);
            rA = dot2(b8, w8.x, rA); rB = dot2(b8, w8.y, rB);
            rA = dot2(b9, w9.x, rA); rB = dot2(b9, w9.y, rB);

            const float gA = bf_lo(s_c) * rA;
            const float gB = bf_hi(s_c) * rB;

            if (seg == 0) {
                acc.x += gA; acc.y += gB;
            } else if (seg == 1) {
                float vA0, vB0, vA1, vB1, vA2, vB2;
                if (VBF) {
                    vA0 = bf_lo(vb0_c); vB0 = bf_hi(vb0_c);
                    vA1 = bf_lo(vb1_c); vB1 = bf_hi(vb1_c);
                    vA2 = bf_lo(vb2_c); vB2 = bf_hi(vb2_c);
                } else {
                    vA0 = vf0_c.x; vB0 = vf0_c.y;
                    vA1 = vf1_c.x; vB1 = vf1_c.y;
                    vA2 = vf2_c.x; vB2 = vf2_c.y;
                }
                av0.x = fmaf(gA, vA0, av0.x); av0.y = fmaf(gB, vB0, av0.y);
                av1.x = fmaf(gA, vA1, av1.x); av1.y = fmaf(gB, vB1, av1.y);
                av2.x = fmaf(gA, vA2, av2.x); av2.y = fmaf(gB, vB2, av2.y);
            } else {
                const float u0 = ed[10], u1 = ed[11], u2 = ed[12];
                av0.x = fmaf(gA, u0, av0.x); av0.y = fmaf(gB, u0, av0.y);
                av1.x = fmaf(gA, u1, av1.x); av1.y = fmaf(gB, u1, av1.y);
                av2.x = fmaf(gA, u2, av2.x); av2.y = fmaf(gB, u2, av2.y);
            }

            // rotate prefetched gathers
            s_c = s_n;
            vb0_c = vb0_n; vb1_c = vb1_n; vb2_c = vb2_n;
            vf0_c = vf0_n; vf1_c = vf1_n; vf2_c = vf2_n;
        }
    }

    // combine: seg2 publishes its delta_v part; seg1 adds and stores.
    __shared__ f32x2 red[2][64][3];
    if (seg == 2) {
        red[nsub][lane][0] = av0;
        red[nsub][lane][1] = av1;
        red[nsub][lane][2] = av2;
    }
    __syncthreads();

    if (seg == 0) {
        __builtin_nontemporal_store(acc, (f32x2*)(out_s + (size_t)j * 128 + c0));
    } else if (seg == 1) {
        const f32x2 o0 = red[nsub][lane][0];
        const f32x2 o1 = red[nsub][lane][1];
        const f32x2 o2 = red[nsub][lane][2];
        float* ov = out_v + (size_t)j * 384;
        f32x2 t;
        t.x = av0.x + o0.x; t.y = av0.y + o0.y;
        __builtin_nontemporal_store(t, (f32x2*)(ov + c0));
        t.x = av1.x + o1.x; t.y = av1.y + o1.y;
        __builtin_nontemporal_store(t, (f32x2*)(ov + 128 + c0));
        t.x = av2.x + o2.x; t.y = av2.y + o2.y;
        __builtin_nontemporal_store(t, (f32x2*)(ov + 256 + c0));
    }
}

extern "C" void kernel_launch(void* const* d_in, const int* in_sizes, int n_in,
                              void* d_out, int out_size, void* d_ws, size_t ws_size,
                              hipStream_t stream) {
    const float* vectors    = (const float*)d_in[0];
    const float* scalars    = (const float*)d_in[1];
    const float* directions = (const float*)d_in[2];
    const int*   idx_i      = (const int*)d_in[3];
    const int*   idx_j      = (const int*)d_in[4];
    const float* W1         = (const float*)d_in[5];
    const float* b1         = (const float*)d_in[6];
    const float* W2         = (const float*)d_in[7];
    const float* b2         = (const float*)d_in[8];
    const float* Wr         = (const float*)d_in[9];
    const float* br         = (const float*)d_in[10];

    float* out_v = (float*)d_out;
    float* out_s = out_v + (size_t)A_NODES * 3 * FEAT;

    // workspace layout (16B-aligned chunks)
    char* ws = (char*)d_ws;
    ushort16* s_bf = (ushort16*)ws;  ws += (size_t)A_NODES * 384 * 2;      // 38.4 MB
    float* edata   = (float*)ws;     ws += (size_t)EDGES * 16 * 4;         // 32.0 MB
    uint32* wrpk   = (uint32*)ws;    ws += (size_t)10 * 384 * 4;           // 15.4 KB
    ushort16* w1pk = (ushort16*)ws;  ws += (size_t)16384 * 2;              // 32 KB
    ushort16* w2pk = (ushort16*)ws;  ws += (size_t)49152 * 2;              // 96 KB
    int* hist      = (int*)ws;       ws += (size_t)A_NODES * 4;
    int* offsets   = (int*)ws;       ws += (((size_t)(A_NODES + 1) * 4 + 15) & ~(size_t)15);
    int* cursor    = (int*)ws;       ws += (size_t)A_NODES * 4;
    ushort16* v_bf = (ushort16*)ws;  ws += (size_t)A_NODES * 384 * 2;      // 38.4 MB (optional)

    const int use_vbf = ((size_t)(ws - (char*)d_ws) <= ws_size) ? 1 : 0;

    hipMemsetAsync(hist, 0, (size_t)A_NODES * 4, stream);

    prep_kernel<<<NB_CVT + NB_HIST + NB_PACK, 256, 0, stream>>>(
        vectors, (uint4*)v_bf, use_vbf, idx_j, hist,
        W1, W2, Wr, w1pk, w2pk, wrpk);

    node_mlp_kernel<<<A_NODES / 16, 256, 0, stream>>>(scalars, w1pk, b1, w2pk, b2, s_bf);
    scan_kernel<<<1, 1024, 0, stream>>>(hist, offsets, cursor);
    edge_prep_kernel<<<(EDGES + 255) / 256, 256, 0, stream>>>(
        directions, idx_i, idx_j, cursor, edata);

    if (use_vbf)
        gather_kernel<1><<<A_NODES / 2, 384, 0, stream>>>(
            s_bf, v_bf, vectors, wrpk, br, edata, offsets, out_v, out_s);
    else
        gather_kernel<0><<<A_NODES / 2, 384, 0, stream>>>(
            s_bf, v_bf, vectors, wrpk, br, edata, offsets, out_v, out_s);
}

// Round 6
// 523.906 us; speedup vs baseline: 1.2467x; 1.2467x over previous
//
#include <hip/hip_runtime.h>
#include <math.h>

#define A_NODES 50000
#define FEAT 128
#define EDGES 500000
#define NRBF 20
#define CUTOFF_F 5.0f
#define PI_OVER_CUTOFF 0.6283185307179586f

typedef unsigned int uint32;
typedef unsigned short ushort16;
typedef short bf16x8 __attribute__((ext_vector_type(8)));
typedef float f32x4 __attribute__((ext_vector_type(4)));
typedef float f32x2 __attribute__((ext_vector_type(2)));

__device__ __forceinline__ ushort16 f2bf(float f) {
    union { float f; uint32 u; } v; v.f = f;
    uint32 r = (v.u + 0x7fffu + ((v.u >> 16) & 1u)) >> 16;   // RNE
    return (ushort16)r;
}
__device__ __forceinline__ uint32 packbf(float a, float b) {
    return (uint32)f2bf(a) | ((uint32)f2bf(b) << 16);
}
__device__ __forceinline__ float bf_lo(uint32 u) { return __uint_as_float(u << 16); }
__device__ __forceinline__ float bf_hi(uint32 u) { return __uint_as_float(u & 0xffff0000u); }

#if __has_builtin(__builtin_amdgcn_fdot2_f32_bf16)
typedef __bf16 bf16x2 __attribute__((ext_vector_type(2)));
__device__ __forceinline__ float dot2(uint32 a, uint32 b, float c) {
    return __builtin_amdgcn_fdot2_f32_bf16(
        __builtin_bit_cast(bf16x2, a), __builtin_bit_cast(bf16x2, b), c, false);
}
#else
__device__ __forceinline__ float dot2(uint32 a, uint32 b, float c) {
    return fmaf(bf_hi(a), bf_hi(b), fmaf(bf_lo(a), bf_lo(b), c));
}
#endif

#define NB_CVT 9375            // ceil(50000*384/8 / 256)
#define NB_HIST 1954           // ceil(500000 / 256)
#define NB_PACK 271            // ceil(69376 / 256)

// ---------------------------------------------------------------------------
// Fused prep: vec_cvt + hist + weight packing (all independent) in one launch.
// ---------------------------------------------------------------------------
__global__ __launch_bounds__(256) void prep_kernel(
    const float* __restrict__ vin, uint4* __restrict__ vbf, int use_vbf,
    const int* __restrict__ idx_j, int* __restrict__ hist,
    const float* __restrict__ W1, const float* __restrict__ W2,
    const float* __restrict__ Wr,
    ushort16* __restrict__ w1pk, ushort16* __restrict__ w2pk,
    uint32* __restrict__ wrpk)
{
    const int b = blockIdx.x;
    if (b < NB_CVT) {
        if (!use_vbf) return;
        const size_t t = (size_t)b * 256 + threadIdx.x;   // 8-float chunk
        const size_t n8 = (size_t)A_NODES * 384 / 8;
        if (t < n8) {
            const float4 f0 = ((const float4*)vin)[2 * t];
            const float4 f1 = ((const float4*)vin)[2 * t + 1];
            uint4 o;
            o.x = packbf(f0.x, f0.y); o.y = packbf(f0.z, f0.w);
            o.z = packbf(f1.x, f1.y); o.w = packbf(f1.z, f1.w);
            vbf[t] = o;
        }
    } else if (b < NB_CVT + NB_HIST) {
        const int e = (b - NB_CVT) * 256 + threadIdx.x;
        if (e < EDGES) atomicAdd(&hist[idx_j[e]], 1);
    } else {
        const int t = (b - NB_CVT - NB_HIST) * 256 + threadIdx.x;
        if (t < 16384) {
            const int jj = t & 7, l = (t >> 3) & 63, kk = (t >> 9) & 3, nt = t >> 11;
            const int col = (l & 15) + 16 * nt;
            const int k   = kk * 32 + (l >> 4) * 8 + jj;
            w1pk[t] = f2bf(W1[k * 128 + col]);
        } else if (t < 16384 + 49152) {
            const int u = t - 16384;
            const int jj = u & 7, l = (u >> 3) & 63, kk = (u >> 9) & 3, nt = u >> 11;
            const int col = (l & 15) + 16 * nt;
            const int k   = kk * 32 + (l >> 4) * 8 + jj;
            w2pk[u] = f2bf(W2[k * 384 + col]);
        } else if (t < 16384 + 49152 + 3840) {
            const int u = t - 16384 - 49152;
            const int m = u / 384, col = u % 384;
            wrpk[u] = packbf(Wr[(2 * m) * 384 + col], Wr[(2 * m + 1) * 384 + col]);
        }
    }
}

// ---------------------------------------------------------------------------
// Node MLP via MFMA. 16 nodes/block, 4 waves.
// ---------------------------------------------------------------------------
__global__ __launch_bounds__(256) void node_mlp_kernel(
    const float* __restrict__ scalars,
    const ushort16* __restrict__ w1pk, const float* __restrict__ bias1,
    const ushort16* __restrict__ w2pk, const float* __restrict__ bias2,
    ushort16* __restrict__ s_bf)
{
    __shared__ ushort16 sc[16][136];
    __shared__ ushort16 hd[16][136];
    const int tx   = threadIdx.x;
    const int lane = tx & 63;
    const int wv   = tx >> 6;                 // 0..3
    const int base = blockIdx.x * 16;

    {
        const int row = tx >> 4;              // 0..15
        const int cs  = (tx & 15) * 8;        // 0,8,...,120
        const float* src = scalars + (size_t)(base + row) * FEAT + cs;
        const float4 f0 = *(const float4*)src;
        const float4 f1 = *(const float4*)(src + 4);
        bf16x8 tmp;
        tmp[0] = (short)f2bf(f0.x); tmp[1] = (short)f2bf(f0.y);
        tmp[2] = (short)f2bf(f0.z); tmp[3] = (short)f2bf(f0.w);
        tmp[4] = (short)f2bf(f1.x); tmp[5] = (short)f2bf(f1.y);
        tmp[6] = (short)f2bf(f1.z); tmp[7] = (short)f2bf(f1.w);
        *(bf16x8*)&sc[row][cs] = tmp;
    }
    __syncthreads();

    const int arow = lane & 15;
    const int kgrp = lane >> 4;               // 0..3

    // ---- layer 1 ----
    f32x4 acc0 = {0.f, 0.f, 0.f, 0.f};
    f32x4 acc1 = {0.f, 0.f, 0.f, 0.f};
    #pragma unroll
    for (int kk = 0; kk < 4; ++kk) {
        const bf16x8 a  = *(const bf16x8*)&sc[arow][kk * 32 + kgrp * 8];
        const bf16x8 b0 = *(const bf16x8*)(w1pk + (((size_t)(wv * 2 + 0) * 4 + kk) * 64 + lane) * 8);
        const bf16x8 b1 = *(const bf16x8*)(w1pk + (((size_t)(wv * 2 + 1) * 4 + kk) * 64 + lane) * 8);
        acc0 = __builtin_amdgcn_mfma_f32_16x16x32_bf16(a, b0, acc0, 0, 0, 0);
        acc1 = __builtin_amdgcn_mfma_f32_16x16x32_bf16(a, b1, acc1, 0, 0, 0);
    }
    {
        const int c0 = wv * 32 + (lane & 15);
        const int c1 = c0 + 16;
        const float bb0 = bias1[c0], bb1 = bias1[c1];
        #pragma unroll
        for (int r = 0; r < 4; ++r) {
            const int row = kgrp * 4 + r;
            float x0 = acc0[r] + bb0;
            float x1 = acc1[r] + bb1;
            x0 = x0 / (1.0f + __expf(-x0));
            x1 = x1 / (1.0f + __expf(-x1));
            hd[row][c0] = f2bf(x0);
            hd[row][c1] = f2bf(x1);
        }
    }
    __syncthreads();

    // ---- layer 2 ----
    f32x4 acc[6];
    #pragma unroll
    for (int n = 0; n < 6; ++n) acc[n] = (f32x4){0.f, 0.f, 0.f, 0.f};
    #pragma unroll
    for (int kk = 0; kk < 4; ++kk) {
        const bf16x8 a = *(const bf16x8*)&hd[arow][kk * 32 + kgrp * 8];
        #pragma unroll
        for (int n = 0; n < 6; ++n) {
            const bf16x8 b = *(const bf16x8*)(w2pk + (((size_t)(wv * 6 + n) * 4 + kk) * 64 + lane) * 8);
            acc[n] = __builtin_amdgcn_mfma_f32_16x16x32_bf16(a, b, acc[n], 0, 0, 0);
        }
    }
    #pragma unroll
    for (int n = 0; n < 6; ++n) {
        const int col = (wv * 6 + n) * 16 + (lane & 15);
        const float bb = bias2[col];
        #pragma unroll
        for (int r = 0; r < 4; ++r) {
            const int row = kgrp * 4 + r;
            s_bf[(size_t)(base + row) * 384 + col] = f2bf(acc[n][r] + bb);
        }
    }
}

// ---------------------------------------------------------------------------
// CSR scan
// ---------------------------------------------------------------------------
__global__ __launch_bounds__(1024) void scan_kernel(
    const int* __restrict__ hist, int* __restrict__ offsets,
    int* __restrict__ cursor)
{
    __shared__ int part[1024];
    const int t = threadIdx.x;
    const int CH = (A_NODES + 1023) / 1024;

    int sum = 0;
    for (int k = 0; k < CH; ++k) {
        const int idx = t * CH + k;
        if (idx < A_NODES) sum += hist[idx];
    }
    part[t] = sum;
    __syncthreads();
    for (int off = 1; off < 1024; off <<= 1) {
        const int v = (t >= off) ? part[t - off] : 0;
        __syncthreads();
        part[t] += v;
        __syncthreads();
    }
    int run = part[t] - sum;
    for (int k = 0; k < CH; ++k) {
        const int idx = t * CH + k;
        if (idx < A_NODES) {
            offsets[idx] = run;
            cursor[idx]  = run;
            run += hist[idx];
        }
    }
    if (t == 0) offsets[A_NODES] = EDGES;
}

// ---------------------------------------------------------------------------
// Edge prep FUSED with scatter: writes edata[pos] directly (plain stores —
// keep lines in L2/L3 for the gather).
// 16 dwords: [0..9] rbf*invn*fc bf16x2 pairs; [10..12] unit dir; [13] fc;
// [14] idx_i bits; [15] pad.
// ---------------------------------------------------------------------------
__global__ __launch_bounds__(256) void edge_prep_kernel(
    const float* __restrict__ directions,
    const int* __restrict__ idx_i, const int* __restrict__ idx_j,
    int* __restrict__ cursor,
    float* __restrict__ edata)
{
    const int e = blockIdx.x * 256 + threadIdx.x;
    if (e >= EDGES) return;
    const int j   = idx_j[e];
    const int pos = atomicAdd(&cursor[j], 1);
    const int i   = idx_i[e];
    const float d0 = directions[(size_t)e * 3 + 0];
    const float d1 = directions[(size_t)e * 3 + 1];
    const float d2 = directions[(size_t)e * 3 + 2];
    const float nr   = sqrtf(d0 * d0 + d1 * d1 + d2 * d2);
    const float invn = 1.0f / nr;
    const float x = PI_OVER_CUTOFF * nr;
    float sx, cx;
    sincosf(x, &sx, &cx);
    const float fc = (nr < CUTOFF_F) ? 0.5f * (cx + 1.0f) : 0.0f;
    const float scale = invn * fc;
    const float twoc = 2.0f * cx;

    float out16[16];
    float s_odd = sx;      // sin((2m+1)x)
    float s_prev = 0.0f;   // sin(2m x)
    #pragma unroll
    for (int m = 0; m < 10; ++m) {
        const float s_even = twoc * s_odd - s_prev;       // sin((2m+2)x)
        out16[m] = __uint_as_float(packbf(s_odd * scale, s_even * scale));
        const float s_next = twoc * s_even - s_odd;       // sin((2m+3)x)
        s_prev = s_even;
        s_odd  = s_next;
    }
    out16[10] = d0 * invn;
    out16[11] = d1 * invn;
    out16[12] = d2 * invn;
    out16[13] = fc;
    out16[14] = __int_as_float(i);
    out16[15] = 0.0f;

    f32x4* dst = (f32x4*)(edata + (size_t)pos * 16);
    dst[0] = (f32x4){out16[0],  out16[1],  out16[2],  out16[3]};
    dst[1] = (f32x4){out16[4],  out16[5],  out16[6],  out16[7]};
    dst[2] = (f32x4){out16[8],  out16[9],  out16[10], out16[11]};
    dst[3] = (f32x4){out16[12], out16[13], out16[14], out16[15]};
}

// ---------------------------------------------------------------------------
// Gather: 2 nodes/block x 2 parity waves (round-0 structure), but:
//  * Wr lives in LDS (15.4 KB staged once per block) -> no per-edge L1
//    weight re-reads (the 196us floor)
//  * edge loop unrolled x2: each ds_read_b64 weight pair feeds 2 edges
//    (4 dot2) -> LDS traffic halved (~60cy/edge)
// Lane owns cols 2*lane, 2*lane+1. Tail edge zeroed via selects.
// ---------------------------------------------------------------------------
template <int VBF>
__global__ __launch_bounds__(256, 4) void gather_kernel(
    const ushort16* __restrict__ s_bf,
    const ushort16* __restrict__ v_bf,
    const float* __restrict__ vectors_f32,
    const uint32* __restrict__ wrpk, const float* __restrict__ br,
    const float* __restrict__ edata,
    const int* __restrict__ offsets,
    float* __restrict__ out_v, float* __restrict__ out_s)
{
    __shared__ uint32 lds_w[3840];            // 15.4 KB packed Wr
    __shared__ float red[4][64][9];           // parity combine

    const int tx   = threadIdx.x;
    const int lane = tx & 63;
    const int wv   = __builtin_amdgcn_readfirstlane(tx >> 6);  // 0..3
    const int nsub = wv >> 1;
    const int par  = wv & 1;
    const int j    = blockIdx.x * 2 + nsub;
    const int c0   = lane * 2;

    // stage Wr -> LDS (coalesced, 15 dwords/thread)
    #pragma unroll
    for (int q = 0; q < 15; ++q)
        lds_w[tx + q * 256] = wrpk[tx + q * 256];
    __syncthreads();

    const float2 brv0 = *(const float2*)(br + c0);
    const float2 brv1 = *(const float2*)(br + 128 + c0);
    const float2 brv2 = *(const float2*)(br + 256 + c0);

    const int beg = offsets[j];
    const int end = offsets[j + 1];

    float accsA = 0.f, accsB = 0.f;
    float avA0 = 0.f, avA1 = 0.f, avA2 = 0.f;
    float avB0 = 0.f, avB1 = 0.f, avB2 = 0.f;

    for (int p = beg + 2 * par; p < end; p += 4) {
        const int p1 = p + 1;
        const int ok1 = (p1 < end);
        const int p1c = ok1 ? p1 : p;

        // ---- load both edata rows (64B each, wave-uniform) ----
        const f32x4* q0p = (const f32x4*)(edata + (size_t)p * 16);
        const f32x4 a0 = q0p[0], a1 = q0p[1], a2 = q0p[2], a3 = q0p[3];
        const f32x4* q1p = (const f32x4*)(edata + (size_t)p1c * 16);
        const f32x4 b0q = q1p[0], b1q = q1p[1], b2q = q1p[2], b3q = q1p[3];

        const int i0 = __float_as_int(a3.z);
        const int i1 = __float_as_int(b3q.z);

        // ---- issue gathers for both edges up front ----
        const ushort16* sr0 = s_bf + (size_t)i0 * 384;
        const uint32 s00 = *(const uint32*)(sr0 + c0);
        const uint32 s01 = *(const uint32*)(sr0 + 128 + c0);
        const uint32 s02 = *(const uint32*)(sr0 + 256 + c0);
        const ushort16* sr1 = s_bf + (size_t)i1 * 384;
        const uint32 s10 = *(const uint32*)(sr1 + c0);
        const uint32 s11 = *(const uint32*)(sr1 + 128 + c0);
        const uint32 s12 = *(const uint32*)(sr1 + 256 + c0);

        float v0A0, v0B0, v0A1, v0B1, v0A2, v0B2;
        float v1A0, v1B0, v1A1, v1B1, v1A2, v1B2;
        if (VBF) {
            const ushort16* vr0 = v_bf + (size_t)i0 * 384;
            const uint32 x0 = *(const uint32*)(vr0 + c0);
            const uint32 x1 = *(const uint32*)(vr0 + 128 + c0);
            const uint32 x2 = *(const uint32*)(vr0 + 256 + c0);
            const ushort16* vr1 = v_bf + (size_t)i1 * 384;
            const uint32 y0 = *(const uint32*)(vr1 + c0);
            const uint32 y1 = *(const uint32*)(vr1 + 128 + c0);
            const uint32 y2 = *(const uint32*)(vr1 + 256 + c0);
            v0A0 = bf_lo(x0); v0B0 = bf_hi(x0);
            v0A1 = bf_lo(x1); v0B1 = bf_hi(x1);
            v0A2 = bf_lo(x2); v0B2 = bf_hi(x2);
            v1A0 = bf_lo(y0); v1B0 = bf_hi(y0);
            v1A1 = bf_lo(y1); v1B1 = bf_hi(y1);
            v1A2 = bf_lo(y2); v1B2 = bf_hi(y2);
        } else {
            const float* vr0 = vectors_f32 + (size_t)i0 * 384;
            v0A0 = vr0[c0];       v0B0 = vr0[c0 + 1];
            v0A1 = vr0[128 + c0]; v0B1 = vr0[129 + c0];
            v0A2 = vr0[256 + c0]; v0B2 = vr0[257 + c0];
            const float* vr1 = vectors_f32 + (size_t)i1 * 384;
            v1A0 = vr1[c0];       v1B0 = vr1[c0 + 1];
            v1A1 = vr1[128 + c0]; v1B1 = vr1[129 + c0];
            v1A2 = vr1[256 + c0]; v1B2 = vr1[257 + c0];
        }

        // rbf dwords
        const uint32 e0m0 = __float_as_uint(a0.x), e0m1 = __float_as_uint(a0.y);
        const uint32 e0m2 = __float_as_uint(a0.z), e0m3 = __float_as_uint(a0.w);
        const uint32 e0m4 = __float_as_uint(a1.x), e0m5 = __float_as_uint(a1.y);
        const uint32 e0m6 = __float_as_uint(a1.z), e0m7 = __float_as_uint(a1.w);
        const uint32 e0m8 = __float_as_uint(a2.x), e0m9 = __float_as_uint(a2.y);
        const uint32 e1m0 = __float_as_uint(b0q.x), e1m1 = __float_as_uint(b0q.y);
        const uint32 e1m2 = __float_as_uint(b0q.z), e1m3 = __float_as_uint(b0q.w);
        const uint32 e1m4 = __float_as_uint(b1q.x), e1m5 = __float_as_uint(b1q.y);
        const uint32 e1m6 = __float_as_uint(b1q.z), e1m7 = __float_as_uint(b1q.w);
        const uint32 e1m8 = __float_as_uint(b2q.x), e1m9 = __float_as_uint(b2q.y);

        const float u00 = a2.z, u01 = a2.w, u02 = a3.x, fc0 = a3.y;
        const float u10 = b2q.z, u11 = b2q.w, u12 = b3q.x, fc1 = b3q.y;

        float r0A0 = fc0 * brv0.x, r0B0 = fc0 * brv0.y;
        float r0A1 = fc0 * brv1.x, r0B1 = fc0 * brv1.y;
        float r0A2 = fc0 * brv2.x, r0B2 = fc0 * brv2.y;
        float r1A0 = fc1 * brv0.x, r1B0 = fc1 * brv0.y;
        float r1A1 = fc1 * brv1.x, r1B1 = fc1 * brv1.y;
        float r1A2 = fc1 * brv2.x, r1B2 = fc1 * brv2.y;

        // weights from LDS: each pair feeds both edges (4 dot2 per load)
#define WSTEP(M, R0, R1) { \
        const uint2 wa = *(const uint2*)&lds_w[(M) * 384 + c0]; \
        const uint2 wb = *(const uint2*)&lds_w[(M) * 384 + 128 + c0]; \
        const uint2 wc = *(const uint2*)&lds_w[(M) * 384 + 256 + c0]; \
        r0A0 = dot2(R0, wa.x, r0A0); r0B0 = dot2(R0, wa.y, r0B0); \
        r0A1 = dot2(R0, wb.x, r0A1); r0B1 = dot2(R0, wb.y, r0B1); \
        r0A2 = dot2(R0, wc.x, r0A2); r0B2 = dot2(R0, wc.y, r0B2); \
        r1A0 = dot2(R1, wa.x, r1A0); r1B0 = dot2(R1, wa.y, r1B0); \
        r1A1 = dot2(R1, wb.x, r1A1); r1B1 = dot2(R1, wb.y, r1B1); \
        r1A2 = dot2(R1, wc.x, r1A2); r1B2 = dot2(R1, wc.y, r1B2); }
        WSTEP(0, e0m0, e1m0)
        WSTEP(1, e0m1, e1m1)
        WSTEP(2, e0m2, e1m2)
        WSTEP(3, e0m3, e1m3)
        WSTEP(4, e0m4, e1m4)
        WSTEP(5, e0m5, e1m5)
        WSTEP(6, e0m6, e1m6)
        WSTEP(7, e0m7, e1m7)
        WSTEP(8, e0m8, e1m8)
        WSTEP(9, e0m9, e1m9)
#undef WSTEP

        // ---- edge 0 accumulate ----
        {
            const float gA1 = bf_lo(s01) * r0A1, gA2 = bf_lo(s02) * r0A2;
            const float gB1 = bf_hi(s01) * r0B1, gB2 = bf_hi(s02) * r0B2;
            accsA = fmaf(bf_lo(s00), r0A0, accsA);
            accsB = fmaf(bf_hi(s00), r0B0, accsB);
            avA0 = fmaf(v0A0, gA1, fmaf(gA2, u00, avA0));
            avB0 = fmaf(v0B0, gB1, fmaf(gB2, u00, avB0));
            avA1 = fmaf(v0A1, gA1, fmaf(gA2, u01, avA1));
            avB1 = fmaf(v0B1, gB1, fmaf(gB2, u01, avB1));
            avA2 = fmaf(v0A2, gA1, fmaf(gA2, u02, avA2));
            avB2 = fmaf(v0B2, gB1, fmaf(gB2, u02, avB2));
        }
        // ---- edge 1 accumulate (zeroed if tail-invalid) ----
        {
            float t0A = bf_lo(s10) * r1A0, t0B = bf_hi(s10) * r1B0;
            float gA1 = bf_lo(s11) * r1A1, gA2 = bf_lo(s12) * r1A2;
            float gB1 = bf_hi(s11) * r1B1, gB2 = bf_hi(s12) * r1B2;
            t0A = ok1 ? t0A : 0.f;  t0B = ok1 ? t0B : 0.f;
            gA1 = ok1 ? gA1 : 0.f;  gA2 = ok1 ? gA2 : 0.f;
            gB1 = ok1 ? gB1 : 0.f;  gB2 = ok1 ? gB2 : 0.f;
            accsA += t0A;
            accsB += t0B;
            avA0 = fmaf(v1A0, gA1, fmaf(gA2, u10, avA0));
            avB0 = fmaf(v1B0, gB1, fmaf(gB2, u10, avB0));
            avA1 = fmaf(v1A1, gA1, fmaf(gA2, u11, avA1));
            avB1 = fmaf(v1B1, gB1, fmaf(gB2, u11, avB1));
            avA2 = fmaf(v1A2, gA1, fmaf(gA2, u12, avA2));
            avB2 = fmaf(v1B2, gB1, fmaf(gB2, u12, avB2));
        }
    }

    // combine the two parity waves per node via LDS
    float* slot = red[wv][lane];
    slot[0] = accsA; slot[1] = accsB;
    slot[2] = avA0;  slot[3] = avB0;
    slot[4] = avA1;  slot[5] = avB1;
    slot[6] = avA2;  slot[7] = avB2;
    __syncthreads();

    if (par == 0) {
        const float* o = red[wv | 1][lane];
        f32x2 t;
        t.x = accsA + o[0]; t.y = accsB + o[1];
        __builtin_nontemporal_store(t, (f32x2*)(out_s + (size_t)j * 128 + c0));
        float* ov = out_v + (size_t)j * 384;
        t.x = avA0 + o[2]; t.y = avB0 + o[3];
        __builtin_nontemporal_store(t, (f32x2*)(ov + c0));
        t.x = avA1 + o[4]; t.y = avB1 + o[5];
        __builtin_nontemporal_store(t, (f32x2*)(ov + 128 + c0));
        t.x = avA2 + o[6]; t.y = avB2 + o[7];
        __builtin_nontemporal_store(t, (f32x2*)(ov + 256 + c0));
    }
}

extern "C" void kernel_launch(void* const* d_in, const int* in_sizes, int n_in,
                              void* d_out, int out_size, void* d_ws, size_t ws_size,
                              hipStream_t stream) {
    const float* vectors    = (const float*)d_in[0];
    const float* scalars    = (const float*)d_in[1];
    const float* directions = (const float*)d_in[2];
    const int*   idx_i      = (const int*)d_in[3];
    const int*   idx_j      = (const int*)d_in[4];
    const float* W1         = (const float*)d_in[5];
    const float* b1         = (const float*)d_in[6];
    const float* W2         = (const float*)d_in[7];
    const float* b2         = (const float*)d_in[8];
    const float* Wr         = (const float*)d_in[9];
    const float* br         = (const float*)d_in[10];

    float* out_v = (float*)d_out;
    float* out_s = out_v + (size_t)A_NODES * 3 * FEAT;

    // workspace layout (16B-aligned chunks)
    char* ws = (char*)d_ws;
    ushort16* s_bf = (ushort16*)ws;  ws += (size_t)A_NODES * 384 * 2;      // 38.4 MB
    float* edata   = (float*)ws;     ws += (size_t)EDGES * 16 * 4;         // 32.0 MB
    uint32* wrpk   = (uint32*)ws;    ws += (size_t)10 * 384 * 4;           // 15.4 KB
    ushort16* w1pk = (ushort16*)ws;  ws += (size_t)16384 * 2;              // 32 KB
    ushort16* w2pk = (ushort16*)ws;  ws += (size_t)49152 * 2;              // 96 KB
    int* hist      = (int*)ws;       ws += (size_t)A_NODES * 4;
    int* offsets   = (int*)ws;       ws += (((size_t)(A_NODES + 1) * 4 + 15) & ~(size_t)15);
    int* cursor    = (int*)ws;       ws += (size_t)A_NODES * 4;
    ushort16* v_bf = (ushort16*)ws;  ws += (size_t)A_NODES * 384 * 2;      // 38.4 MB (optional)

    const int use_vbf = ((size_t)(ws - (char*)d_ws) <= ws_size) ? 1 : 0;

    hipMemsetAsync(hist, 0, (size_t)A_NODES * 4, stream);

    prep_kernel<<<NB_CVT + NB_HIST + NB_PACK, 256, 0, stream>>>(
        vectors, (uint4*)v_bf, use_vbf, idx_j, hist,
        W1, W2, Wr, w1pk, w2pk, wrpk);

    node_mlp_kernel<<<A_NODES / 16, 256, 0, stream>>>(scalars, w1pk, b1, w2pk, b2, s_bf);
    scan_kernel<<<1, 1024, 0, stream>>>(hist, offsets, cursor);
    edge_prep_kernel<<<(EDGES + 255) / 256, 256, 0, stream>>>(
        directions, idx_i, idx_j, cursor, edata);

    if (use_vbf)
        gather_kernel<1><<<A_NODES / 2, 256, 0, stream>>>(
            s_bf, v_bf, vectors, wrpk, br, edata, offsets, out_v, out_s);
    else
        gather_kernel<0><<<A_NODES / 2, 256, 0, stream>>>(
            s_bf, v_bf, vectors, wrpk, br, edata, offsets, out_v, out_s);
}